// Round 16
// baseline (145.371 us; speedup 1.0000x reference)
//
#include <hip/hip_runtime.h>

#define N_IMG   1024
#define N_VIEWS 90
#define CENTER  512
#define TILE    64
#define NTPB    8                   // y-tiles per block
#define NTHREADS 512
#define NWAVES   8
#define YPT      (TILE / NWAVES)    // 8 samples per thread per tile
#define TILE_WORDS 9216             // >= 93*97+95 (raw-bbox + drift pad); 36.9 KB

// x_in =  ca*X + sa*Y + cx,  cx = CENTER*(1 - ca - sa)
// y_in = -sa*X + ca*Y + cy,  cy = CENTER*(1 - ca + sa)
// Fixed fmaf chain: corner extremes == sample extremes (monotone per variable).
__device__ __forceinline__ void map_coords(float ca, float sa, float cx, float cy,
                                           float Xf, float Yf,
                                           float& x_in, float& y_in) {
    const float fx0 = fmaf(ca, Xf, cx);
    const float fy0 = fmaf(-sa, Xf, cy);
    x_in = fmaf(sa, Yf, fx0);
    y_in = fmaf(ca, Yf, fy0);
}

__device__ __forceinline__ void gload_lds4(const float* g, float* l) {
    __builtin_amdgcn_global_load_lds((const __attribute__((address_space(1))) void*)g,
                                     (__attribute__((address_space(3))) void*)l, 4, 0, 0);
}
__device__ __forceinline__ void gload_lds16(const float* g, float* l) {
    __builtin_amdgcn_global_load_lds((const __attribute__((address_space(1))) void*)g,
                                     (__attribute__((address_space(3))) void*)l, 16, 0, 0);
}

// R12's proven fp32 sampler: pairs on float2 ext-vectors -> packed fp32 VALU.
typedef float v2f __attribute__((ext_vector_type(2)));

template<int STRIDE>
__device__ __forceinline__ float sample_tile(const float* __restrict__ tile,
                                             float sa, float ca,
                                             float x_in, float y_in, float basef) {
    const float Sf = (float)STRIDE;
    v2f x2 = {x_in, x_in + sa};
    v2f y2 = {y_in, y_in + ca};
    const v2f dx2 = {2.0f * sa, 2.0f * sa};
    const v2f dy2 = {2.0f * ca, 2.0f * ca};
    const v2f S2  = {Sf, Sf};
    const v2f b2  = {basef, basef};
    v2f acc2 = {0.0f, 0.0f};
    #pragma unroll
    for (int p = 0; p < YPT / 2; ++p) {
        v2f x0f = {floorf(x2.x), floorf(x2.y)};
        v2f y0f = {floorf(y2.x), floorf(y2.y)};
        const v2f wx = x2 - x0f;
        const v2f wy = y2 - y0f;
        const v2f lif = y0f * S2 + x0f + b2;     // exact in fp32 (< 2^23)
        const int li0 = (int)lif.x;
        const int li1 = (int)lif.y;
        const v2f t00 = {tile[li0],              tile[li1]};
        const v2f t01 = {tile[li0 + 1],          tile[li1 + 1]};
        const v2f t10 = {tile[li0 + STRIDE],     tile[li1 + STRIDE]};
        const v2f t11 = {tile[li0 + STRIDE + 1], tile[li1 + STRIDE + 1]};
        const v2f top = (t01 - t00) * wx + t00;
        const v2f bot = (t11 - t10) * wx + t10;
        acc2 += (bot - top) * wy + top;
        x2 += dx2; y2 += dy2;
    }
    return acc2.x + acc2.y;
}

// Per-tile block-uniform params (R12 logic verbatim). dst layout:
// [0]=iy0, [1]=nrows, [2]=win, [3]=dB, [4]=path, [5]=flags, [6]=ry0
__device__ __forceinline__ void compute_params(int* dst, int X0, int Y0,
                                               float sa, float ca, float cx, float cy,
                                               bool store) {
    float x00, y00, x01, y01, x10, y10, x11, y11;
    map_coords(ca, sa, cx, cy, (float)X0,        (float)Y0,        x00, y00);
    map_coords(ca, sa, cx, cy, (float)(X0 + 63), (float)Y0,        x01, y01);
    map_coords(ca, sa, cx, cy, (float)X0,        (float)(Y0 + 63), x10, y10);
    map_coords(ca, sa, cx, cy, (float)(X0 + 63), (float)(Y0 + 63), x11, y11);
    const float xmin = fminf(fminf(x00, x01), fminf(x10, x11));
    const float xmax = fmaxf(fmaxf(x00, x01), fmaxf(x10, x11));
    const float ymin = fminf(fminf(y00, y01), fminf(y10, y11));
    const float ymax = fmaxf(fmaxf(y00, y01), fmaxf(y10, y11));

    const int ix0_raw = (int)floorf(xmin);
    const int ix1_raw = (int)floorf(xmax) + 1;   // max x-tap; span <= 91
    const int iy0_raw = (int)floorf(ymin);
    const int iy1_raw = (int)floorf(ymax) + 1;   // max y-tap; span <= 91

    const bool empty = (ix1_raw < 0) || (ix0_raw > N_IMG - 1) ||
                       (iy1_raw < 0) || (iy0_raw > N_IMG - 1);
    const bool interior = (ix0_raw >= 0) && (ix1_raw <= N_IMG - 1) &&
                          (iy0_raw >= 0) && (iy1_raw <= N_IMG - 1);

    int path = (fabsf(ca) > 0.7072f) ? 0 : ((ca > 0.0f) ? 1 : 2);
    int iy0w = iy0_raw, win = 0, dB = 0, ry0 = 0, nrows = 0;
    if (interior) {
        if (path == 0) {
            win = min(ix0_raw & ~3, N_IMG - 96);          // 96-px in-image window
        } else {
            win = min(ix0_raw, N_IMG - 64);               // dual 64-px segments
            dB  = max(win, ix1_raw - 63) - win;           // 0..28
        }
        nrows = iy1_raw - iy0_raw + 1;                    // <= 92 (staged rows)
    } else {
        // border: RAW (unclamped) 4-aligned window; zeros pad off-image.
        win  = ix0_raw & ~3;                              // col offset <= 94 < 95
        ry0  = max(0, iy0_raw);                           // in-image rows to stage
        nrows = min(N_IMG - 1, iy1_raw) - ry0 + 1;
    }
    if (store) {
        dst[0] = iy0w; dst[1] = nrows; dst[2] = win; dst[3] = dB;
        dst[4] = path; dst[5] = empty ? 1 : (interior ? 2 : 0); dst[6] = ry0;
    }
}

__global__ __launch_bounds__(NTHREADS) void radon_tile(const float* __restrict__ img,
                                                       const float* __restrict__ theta,
                                                       float* __restrict__ out) {
    __shared__ float tile[TILE_WORDS];   // 36.9 KB -> 4 blocks/CU, 32 waves
    __shared__ float fpar[4];            // sa, ca, cx, cy
    __shared__ int   ipar[2][8];         // double-slot per-tile params

    const int a  = blockIdx.z;
    const int X0 = blockIdx.x * TILE;
    const int tb = blockIdx.y * NTPB;    // first y-tile of this block
    const int tid  = threadIdx.x;
    const int lane = tid & 63;
    const int wv   = tid >> 6;           // 0..7

    // ---- once-per-block preamble (wave 0): angle + params(tile 0) ----
    if (wv == 0) {
        const float ang = theta[a] * 0.017453292519943295f;
        float sa, ca;
        __sincosf(ang, &sa, &ca);
        const float cx = (float)CENTER * (1.0f - ca - sa);
        const float cy = (float)CENTER * (1.0f - ca + sa);
        if (tid == 0) { fpar[0] = sa; fpar[1] = ca; fpar[2] = cx; fpar[3] = cy; }
        compute_params(ipar[0], X0, tb * TILE, sa, ca, cx, cy, tid == 0);
    }
    __syncthreads();

    const float sa = fpar[0], ca = fpar[1], cx = fpar[2], cy = fpar[3];
    const float Xf  = (float)(X0 + lane);
    const float fx0 = fmaf(ca, Xf, cx);
    const float fy0 = fmaf(-sa, Xf, cy);

    float acc = 0.0f;

    #pragma unroll 1
    for (int t = 0; t < NTPB; ++t) {
        const int* P = ipar[t & 1];
        const int iy0 = P[0], nrows = P[1], win = P[2], dB = P[3];
        const int path = P[4], flags = P[5], ry0 = P[6];
        const int S = (path == 0) ? 96 : ((path == 1) ? 95 : 97);

        if (!(flags & 1)) {
            if (flags & 2) {
                // ---- interior staging: async DMA (no VGPR round-trip) ----
                if (path == 0) {
                    const int D = nrows * 96;
                    for (int o = wv * 256; o < D; o += NWAVES * 256) {
                        const int d = o + 4 * lane;
                        const int r = (unsigned)d / 96u;
                        const int c = d - r * 96;
                        const int gr = min(iy0 + r, N_IMG - 1);   // overshoot clamp
                        gload_lds16(img + (size_t)gr * N_IMG + win + c, tile + o);
                    }
                } else {
                    const float* g = img + (size_t)(iy0 + wv) * N_IMG + win + lane;
                    float* l = tile + wv * S;
                    for (int r = wv; r < nrows; r += NWAVES) {
                        gload_lds4(g, l);
                        if (dB > 0) gload_lds4(g + dB, l + dB);
                        g += NWAVES * N_IMG;
                        l += NWAVES * S;
                    }
                }
            } else {
                // ---- border staging: zero-fill + guarded float4 copy ----
                for (int o4 = tid; o4 < TILE_WORDS / 4; o4 += NTHREADS)
                    *(float4*)(tile + 4 * o4) = make_float4(0.f, 0.f, 0.f, 0.f);
                __syncthreads();                      // block-uniform branch
                const int cx0 = max(0, win);          // 4-aligned
                const int cxe = min(N_IMG - 1, win + 94);
                const int wIn = cxe - cx0 + 1;        // 1..95
                const int n4  = wIn >> 2;
                const int items = nrows * 24;
                for (int idx = tid; idx < items; idx += NTHREADS) {
                    const int r  = (unsigned)idx / 24u;
                    const int c4 = idx - r * 24;
                    const int gy = ry0 + r;
                    float* dst = tile + (gy - iy0) * S + (cx0 - win) + 4 * c4;
                    const float* src = img + (size_t)gy * N_IMG + cx0 + 4 * c4;
                    if (c4 < n4) {
                        *(float4*)dst = *(const float4*)src;
                    } else if (c4 == n4) {
                        for (int j = 0; j < (wIn & 3); ++j) dst[j] = src[j];
                    }
                }
            }
        }

        // wave 0 computes next tile's params while staging DMAs are in flight
        if (wv == 0 && t + 1 < NTPB)
            compute_params(ipar[(t + 1) & 1], X0, (tb + t + 1) * TILE,
                           sa, ca, cx, cy, tid == 0);

        __syncthreads();   // drains staging DMAs; publishes params t+1

        if (!(flags & 1)) {
            const float Ybf = (float)((tb + t) * TILE + wv * YPT);
            const float x_in = fmaf(sa, Ybf, fx0);
            const float y_in = fmaf(ca, Ybf, fy0);
            const float basef = -(float)(iy0 * S + win);
            if (path == 0)      acc += sample_tile<96>(tile, sa, ca, x_in, y_in, basef);
            else if (path == 1) acc += sample_tile<95>(tile, sa, ca, x_in, y_in, basef);
            else                acc += sample_tile<97>(tile, sa, ca, x_in, y_in, basef);
        }

        __syncthreads();   // WAR: tile reused by next iteration's staging
    }

    // ---- block reduce (overlay tile) + one atomic per X (2 contributors) ----
    tile[wv * 64 + lane] = acc;
    __syncthreads();
    if (wv == 0) {
        float s = 0.0f;
        #pragma unroll
        for (int w = 0; w < NWAVES; ++w) s += tile[w * 64 + lane];
        atomicAdd(&out[(size_t)(X0 + lane) * N_VIEWS + a], s);
    }
}

extern "C" void kernel_launch(void* const* d_in, const int* in_sizes, int n_in,
                              void* d_out, int out_size, void* d_ws, size_t ws_size,
                              hipStream_t stream) {
    const float* img   = (const float*)d_in[0];   // [1024, 1024] f32
    const float* theta = (const float*)d_in[1];   // [90] f32 degrees
    float* out = (float*)d_out;                   // [1024, 90] f32

    (void)hipMemsetAsync(d_out, 0, (size_t)out_size * sizeof(float), stream);

    // Block = (X-tile, y-half, angle); each block covers 8 y-tiles.
    dim3 grid(N_IMG / TILE, (N_IMG / TILE) / NTPB, N_VIEWS);   // 16 x 2 x 90
    radon_tile<<<grid, NTHREADS, 0, stream>>>(img, theta, out);
}

// Round 17
// 139.933 us; speedup vs baseline: 1.0389x; 1.0389x over previous
//
#include <hip/hip_runtime.h>

#define N_IMG   1024
#define N_VIEWS 90
#define CENTER  512
#define TILE    64
#define NYB     (N_IMG / TILE)      // 16 y-blocks
#define NTHREADS 512
#define NWAVES   8
#define YPT      (TILE / NWAVES)    // 8 samples per thread
#define TILE_WORDS 9216             // >= 93*97+95 (raw-bbox + drift pad); 36.9 KB

typedef float v2f __attribute__((ext_vector_type(2)));

// x_in =  ca*X + sa*Y + cx,  cx = CENTER*(1 - ca - sa)
// y_in = -sa*X + ca*Y + cy,  cy = CENTER*(1 - ca + sa)
// Fixed fmaf chain: corner extremes == sample extremes (monotone per variable).
__device__ __forceinline__ void map_coords(float ca, float sa, float cx, float cy,
                                           float Xf, float Yf,
                                           float& x_in, float& y_in) {
    const float fx0 = fmaf(ca, Xf, cx);
    const float fy0 = fmaf(-sa, Xf, cy);
    x_in = fmaf(sa, Yf, fx0);
    y_in = fmaf(ca, Yf, fy0);
}

__device__ __forceinline__ void gload_lds4(const float* g, float* l) {
    __builtin_amdgcn_global_load_lds((const __attribute__((address_space(1))) void*)g,
                                     (__attribute__((address_space(3))) void*)l, 4, 0, 0);
}
__device__ __forceinline__ void gload_lds16(const float* g, float* l) {
    __builtin_amdgcn_global_load_lds((const __attribute__((address_space(1))) void*)g,
                                     (__attribute__((address_space(3))) void*)l, 16, 0, 0);
}

// Fast bilinear sampler — the only sample path. Samples processed in pairs on
// float2 ext-vectors so mul/add/fma issue as packed fp32 (v_pk_*, 2x rate);
// floor/cvt stay scalar. HIP's default -ffp-contract=fast fuses a*b+c.
// Incremental coords: <=6 packed adds, drift <=4e-4 px; buffer padded so a
// +-1 floor overshoot stays in-bounds (weight ~0 there).
template<int STRIDE>
__device__ __forceinline__ float sample_tile(const float* __restrict__ tile,
                                             float sa, float ca,
                                             float x_in, float y_in, float basef) {
    const float Sf = (float)STRIDE;
    v2f x2 = {x_in, x_in + sa};
    v2f y2 = {y_in, y_in + ca};
    const v2f dx2 = {2.0f * sa, 2.0f * sa};
    const v2f dy2 = {2.0f * ca, 2.0f * ca};
    const v2f S2  = {Sf, Sf};
    const v2f b2  = {basef, basef};
    v2f acc2 = {0.0f, 0.0f};
    #pragma unroll
    for (int p = 0; p < YPT / 2; ++p) {
        v2f x0f = {floorf(x2.x), floorf(x2.y)};
        v2f y0f = {floorf(y2.x), floorf(y2.y)};
        const v2f wx = x2 - x0f;                 // v_pk_add
        const v2f wy = y2 - y0f;
        const v2f lif = y0f * S2 + x0f + b2;     // v_pk_fma + v_pk_add (exact <2^23)
        const int li0 = (int)lif.x;
        const int li1 = (int)lif.y;
        const v2f t00 = {tile[li0],              tile[li1]};              // ds_read2
        const v2f t01 = {tile[li0 + 1],          tile[li1 + 1]};
        const v2f t10 = {tile[li0 + STRIDE],     tile[li1 + STRIDE]};     // ds_read2
        const v2f t11 = {tile[li0 + STRIDE + 1], tile[li1 + STRIDE + 1]};
        const v2f top = (t01 - t00) * wx + t00;  // pk_sub + pk_fma
        const v2f bot = (t11 - t10) * wx + t10;
        acc2 += (bot - top) * wy + top;          // pk_sub + pk_fma + pk_add
        x2 += dx2; y2 += dy2;                    // pk_add x2
    }
    return acc2.x + acc2.y;
}

__global__ __launch_bounds__(NTHREADS) void radon_tile(const float* __restrict__ img,
                                                       const float* __restrict__ theta,
                                                       float* __restrict__ partial,
                                                       float* __restrict__ out,
                                                       int mode) {
    __shared__ float tile[TILE_WORDS];   // 36.9 KB -> 4 blocks/CU, 32 waves
    __shared__ float fpar[4];            // sa, ca, cx, cy
    __shared__ int   ipar[8];            // iy0, nrows, win, dB, path, flags, ry0

    const int a  = blockIdx.z;
    const int X0 = blockIdx.x * TILE;
    const int Y0 = blockIdx.y * TILE;
    const int tid  = threadIdx.x;
    const int lane = tid & 63;
    const int wv   = tid >> 6;            // 0..7

    // ---- wave 0 computes all block-uniform params once ----
    if (wv == 0) {
        const float ang = theta[a] * 0.017453292519943295f;
        float sa, ca;
        __sincosf(ang, &sa, &ca);
        const float cx = (float)CENTER * (1.0f - ca - sa);
        const float cy = (float)CENTER * (1.0f - ca + sa);

        float x00, y00, x01, y01, x10, y10, x11, y11;
        map_coords(ca, sa, cx, cy, (float)X0,        (float)Y0,        x00, y00);
        map_coords(ca, sa, cx, cy, (float)(X0 + 63), (float)Y0,        x01, y01);
        map_coords(ca, sa, cx, cy, (float)X0,        (float)(Y0 + 63), x10, y10);
        map_coords(ca, sa, cx, cy, (float)(X0 + 63), (float)(Y0 + 63), x11, y11);
        const float xmin = fminf(fminf(x00, x01), fminf(x10, x11));
        const float xmax = fmaxf(fmaxf(x00, x01), fmaxf(x10, x11));
        const float ymin = fminf(fminf(y00, y01), fminf(y10, y11));
        const float ymax = fmaxf(fmaxf(y00, y01), fmaxf(y10, y11));

        const int ix0_raw = (int)floorf(xmin);
        const int ix1_raw = (int)floorf(xmax) + 1;   // max x-tap; span <= 91
        const int iy0_raw = (int)floorf(ymin);
        const int iy1_raw = (int)floorf(ymax) + 1;   // max y-tap; span <= 91

        const bool empty = (ix1_raw < 0) || (ix0_raw > N_IMG - 1) ||
                           (iy1_raw < 0) || (iy0_raw > N_IMG - 1);
        const bool interior = (ix0_raw >= 0) && (ix1_raw <= N_IMG - 1) &&
                              (iy0_raw >= 0) && (iy1_raw <= N_IMG - 1);

        int path = (fabsf(ca) > 0.7072f) ? 0 : ((ca > 0.0f) ? 1 : 2);
        int iy0w, win, dB = 0, ry0 = 0, nrows = 0;
        if (interior) {
            iy0w = iy0_raw;
            if (path == 0) {
                win = min(ix0_raw & ~3, N_IMG - 96);          // 96-px in-image window
            } else {
                win = min(ix0_raw, N_IMG - 64);               // dual 64-px segments
                dB  = max(win, ix1_raw - 63) - win;           // 0..28
            }
            nrows = iy1_raw - iy0_raw + 1;                    // <= 92 (staged rows)
        } else {
            // border: RAW (unclamped) 4-aligned window; zeros pad off-image.
            iy0w = iy0_raw;
            win  = ix0_raw & ~3;                              // col offset <= 94 < 95
            ry0  = max(0, iy0_raw);                           // in-image rows to stage
            nrows = min(N_IMG - 1, iy1_raw) - ry0 + 1;
        }
        if (tid == 0) {
            fpar[0] = sa; fpar[1] = ca; fpar[2] = cx; fpar[3] = cy;
            ipar[0] = iy0w; ipar[1] = nrows; ipar[2] = win; ipar[3] = dB;
            ipar[4] = path;
            ipar[5] = empty ? 1 : (interior ? 2 : 0);
            ipar[6] = ry0;
        }
    }
    __syncthreads();

    float* __restrict__ pslot = partial + ((size_t)(a * NYB + blockIdx.y) << 10) + X0;
    const int flags = ipar[5];

    if (flags & 1) {                        // tile maps fully outside image
        if (mode == 0 && tid < 64) pslot[tid] = 0.0f;
        return;                             // mode 1: out pre-zeroed
    }

    const float sa = fpar[0], ca = fpar[1], cx = fpar[2], cy = fpar[3];
    const int iy0 = ipar[0], nrows = ipar[1], win = ipar[2], dB = ipar[3];
    const int path = ipar[4];
    const int S = (path == 0) ? 96 : ((path == 1) ? 95 : 97);

    if (flags & 2) {
        // ---- interior staging: async DMA (no VGPR round-trip) ----
        if (path == 0) {
            const int D = nrows * 96;
            for (int o = wv * 256; o < D; o += NWAVES * 256) {
                const int d = o + 4 * lane;
                const int r = (unsigned)d / 96u;
                const int c = d - r * 96;
                const int gr = min(iy0 + r, N_IMG - 1);       // overshoot clamp
                gload_lds16(img + (size_t)gr * N_IMG + win + c, tile + o);
            }
        } else {
            const float* g = img + (size_t)(iy0 + wv) * N_IMG + win + lane;
            float* l = tile + wv * S;
            for (int r = wv; r < nrows; r += NWAVES) {
                gload_lds4(g, l);
                if (dB > 0) gload_lds4(g + dB, l + dB);
                g += NWAVES * N_IMG;
                l += NWAVES * S;
            }
        }
    } else {
        // ---- border staging: zero-fill, then guarded float4 copy of the
        //      in-image intersection; samples then use the SAME fast path ----
        for (int o4 = tid; o4 < TILE_WORDS / 4; o4 += NTHREADS)
            *(float4*)(tile + 4 * o4) = make_float4(0.f, 0.f, 0.f, 0.f);
        __syncthreads();
        const int ry0 = ipar[6];
        const int cx0 = max(0, win);                          // 4-aligned
        const int cxe = min(N_IMG - 1, win + 94);             // last needed col
        const int wIn = cxe - cx0 + 1;                        // 1..95
        const int n4  = wIn >> 2;                             // full float4 chunks
        const int items = nrows * 24;
        for (int idx = tid; idx < items; idx += NTHREADS) {
            const int r  = (unsigned)idx / 24u;
            const int c4 = idx - r * 24;
            const int gy = ry0 + r;
            float* dst = tile + (gy - iy0) * S + (cx0 - win) + 4 * c4;
            const float* src = img + (size_t)gy * N_IMG + cx0 + 4 * c4;
            if (c4 < n4) {
                *(float4*)dst = *(const float4*)src;          // ds_write_b128
            } else if (c4 == n4) {
                for (int j = 0; j < (wIn & 3); ++j) dst[j] = src[j];
            }
        }
    }
    __syncthreads();

    // ---- per-lane sample line; single fast path ----
    const float Xf  = (float)(X0 + lane);
    const float fx0 = fmaf(ca, Xf, cx);
    const float fy0 = fmaf(-sa, Xf, cy);
    const float Ybf = (float)(Y0 + wv * YPT);
    const float x_in = fmaf(sa, Ybf, fx0);
    const float y_in = fmaf(ca, Ybf, fy0);
    const float basef = -(float)(iy0 * S + win);

    float acc;
    if (path == 0)      acc = sample_tile<96>(tile, sa, ca, x_in, y_in, basef);
    else if (path == 1) acc = sample_tile<95>(tile, sa, ca, x_in, y_in, basef);
    else                acc = sample_tile<97>(tile, sa, ca, x_in, y_in, basef);

    // ---- block reduce, overlaying tile; plain store (mode 0) or atomic ----
    __syncthreads();                        // all waves done reading tile
    tile[wv * 64 + lane] = acc;
    __syncthreads();
    if (wv == 0) {
        float s = 0.0f;
        #pragma unroll
        for (int w = 0; w < NWAVES; ++w) s += tile[w * 64 + lane];
        if (mode == 0) pslot[lane] = s;
        else           atomicAdd(&out[(X0 + lane) * N_VIEWS + a], s);
    }
}

__global__ __launch_bounds__(256) void reduce_partials(const float* __restrict__ partial,
                                                       float* __restrict__ out) {
    const int g = blockIdx.x * 256 + threadIdx.x;   // [0, 90*1024)
    const int a = g >> 10;
    const int X = g & 1023;
    float s = 0.0f;
    #pragma unroll
    for (int yb = 0; yb < NYB; ++yb)
        s += partial[((size_t)(a * NYB + yb) << 10) + X];
    out[X * N_VIEWS + a] = s;
}

extern "C" void kernel_launch(void* const* d_in, const int* in_sizes, int n_in,
                              void* d_out, int out_size, void* d_ws, size_t ws_size,
                              hipStream_t stream) {
    const float* img   = (const float*)d_in[0];   // [1024, 1024] f32
    const float* theta = (const float*)d_in[1];   // [90] f32 degrees
    float* out     = (float*)d_out;               // [1024, 90] f32
    float* partial = (float*)d_ws;                // [90][16][1024] f32 partials

    const size_t needed = (size_t)N_VIEWS * NYB * N_IMG * sizeof(float);  // 5.9 MB
    const int mode = (ws_size >= needed) ? 0 : 1;
    if (mode == 1)
        (void)hipMemsetAsync(d_out, 0, (size_t)out_size * sizeof(float), stream);

    dim3 grid(N_IMG / TILE, N_IMG / TILE, N_VIEWS);   // 16 x 16 x 90, one dispatch
    radon_tile<<<grid, NTHREADS, 0, stream>>>(img, theta, partial, out, mode);

    if (mode == 0)
        reduce_partials<<<(N_VIEWS * N_IMG) / 256, 256, 0, stream>>>(partial, out);
}